// Round 9
// baseline (1360.242 us; speedup 1.0000x reference)
//
#include <hip/hip_runtime.h>
#include <math.h>

// Problem constants
#define VOCAB 10000
#define D 512
#define L 6
#define H 8
#define B 32
#define S 384
#define DK 64
#define DFF 2048
#define TOK (B * S)            // 12288 tokens
#define TD ((size_t)TOK * D)   // 6291456 elements per activation buffer

typedef unsigned short u16;
using bf16x8 = __attribute__((ext_vector_type(8))) short;
using f32x4  = __attribute__((ext_vector_type(4))) float;
using u16x4  = __attribute__((ext_vector_type(4))) unsigned short;

// ---------------------------------------------------------------------------
// Static workspace
__device__ u16   g_x[TD];                  // residual stream bf16
__device__ u16   g_h[TD];                  // LN out / attn out bf16
__device__ u16   g_q[TD];                  // Q bf16 [TOK][D]
__device__ u16   g_k[TD];                  // K bf16 [TOK][D]
__device__ u16   g_vt[TD];                 // V^T bf16 [B][H][DK][S]
__device__ u16   g_ffn[(size_t)TOK * DFF]; // FFN act bf16
// Weights in MFMA-fragment-linear layout: frag f = nb*(K/32)+kb, 1KB each:
// Bp[f*512 + lane*8 + j] = W^T[nb*16 + (lane&15)][kb*32 + (lane>>4)*8 + j]
__device__ u16   g_qkvB[(size_t)L * 3 * D * D];
__device__ u16   g_woB[(size_t)L * D * D];
__device__ u16   g_w1B[(size_t)L * DFF * D];
__device__ u16   g_w2B[(size_t)L * D * DFF];
__device__ float g_bqkv[L * 3 * D];
__device__ float g_pool[B * 6 * D];

__device__ __forceinline__ u16 f2bf(float f) {
  unsigned int u = __builtin_bit_cast(unsigned int, f);
  u = (u + 0x7fffu + ((u >> 16) & 1u)) >> 16;
  return (u16)u;
}
__device__ __forceinline__ float bf2f(u16 v) {
  unsigned int u = ((unsigned int)v) << 16;
  return __builtin_bit_cast(float, u);
}

__device__ __forceinline__ void gld16(const void* g, void* l) {
  __builtin_amdgcn_global_load_lds(
      (const __attribute__((address_space(1))) unsigned int*)g,
      (__attribute__((address_space(3))) unsigned int*)l, 16, 0, 0);
}

// ---------------------------------------------------------------------------
__global__ __launch_bounds__(256) void embed_kernel(
    const int* __restrict__ ids, const float* __restrict__ inten,
    const float* __restrict__ emb, const float* __restrict__ iw,
    const float* __restrict__ ib, u16* __restrict__ x) {
  int tok = blockIdx.x;
  int t = threadIdx.x;
  int id = ids[tok];
  float it = inten[tok];
  const float* er = emb + (size_t)id * D;
  u16* xr = x + (size_t)tok * D;
  xr[t]       = f2bf(er[t] + it * iw[t] + ib[t]);
  xr[t + 256] = f2bf(er[t + 256] + it * iw[t + 256] + ib[t + 256]);
}

// ---------------------------------------------------------------------------
// LayerNorm bf16 -> bf16. Wave-per-token, vectorized.
__global__ __launch_bounds__(256) void ln_kernel(
    const u16* __restrict__ x, const float* __restrict__ w,
    const float* __restrict__ b, u16* __restrict__ out) {
  int tok = blockIdx.x * 4 + (threadIdx.x >> 6);
  int lane = threadIdx.x & 63;
  const u16* xr = x + (size_t)tok * D + lane * 8;
  bf16x8 v8 = *(const bf16x8*)xr;
  float v[8];
  float s = 0.f, ss = 0.f;
  #pragma unroll
  for (int i = 0; i < 8; ++i) {
    v[i] = bf2f((u16)v8[i]);
    s += v[i];
    ss += v[i] * v[i];
  }
  #pragma unroll
  for (int o = 1; o < 64; o <<= 1) {
    s += __shfl_xor(s, o);
    ss += __shfl_xor(ss, o);
  }
  float mean = s * (1.0f / (float)D);
  float var = ss * (1.0f / (float)D) - mean * mean;
  float rstd = rsqrtf(var + 1e-5f);
  float4 w0 = *(const float4*)(w + lane * 8);
  float4 w1 = *(const float4*)(w + lane * 8 + 4);
  float4 b0 = *(const float4*)(b + lane * 8);
  float4 b1 = *(const float4*)(b + lane * 8 + 4);
  float wv[8] = {w0.x, w0.y, w0.z, w0.w, w1.x, w1.y, w1.z, w1.w};
  float bv[8] = {b0.x, b0.y, b0.z, b0.w, b1.x, b1.y, b1.z, b1.w};
  bf16x8 o8;
  #pragma unroll
  for (int i = 0; i < 8; ++i)
    o8[i] = (short)f2bf((v[i] - mean) * rstd * wv[i] + bv[i]);
  *(bf16x8*)(out + (size_t)tok * D + lane * 8) = o8;
}

// ---------------------------------------------------------------------------
// B fragment prepack: W fp32 [K][N] -> fragment-linear bf16.
// block = 4 frags x 64 lanes.
__global__ __launch_bounds__(256) void prepack_b(
    const float* __restrict__ W, u16* __restrict__ Bp,
    int N, int K, size_t sstride, size_t dstride) {
  int l = blockIdx.y;
  W += (size_t)l * sstride;
  Bp += (size_t)l * dstride;
  int fi = blockIdx.x * 4 + (threadIdx.x >> 6);
  int lane = threadIdx.x & 63;
  int nfr = K >> 5;
  int nb = fi / nfr, kb = fi - nb * nfr;
  int col = nb * 16 + (lane & 15);
  int row0 = kb * 32 + (lane >> 4) * 8;
  bf16x8 o;
  #pragma unroll
  for (int j = 0; j < 8; ++j)
    o[j] = (short)f2bf(W[(size_t)(row0 + j) * N + col]);
  *(bf16x8*)(Bp + (size_t)fi * 512 + lane * 8) = o;
}

__global__ __launch_bounds__(256) void concat_bias(
    const float* __restrict__ bq, const float* __restrict__ bk,
    const float* __restrict__ bv, float* __restrict__ dst) {
  int i = blockIdx.x * 256 + threadIdx.x;  // L*1536
  int l = i / 1536, c = i % 1536;
  float v = (c < 512) ? bq[l * 512 + c]
          : (c < 1024) ? bk[l * 512 + c - 512]
                       : bv[l * 512 + c - 1024];
  dst[i] = v;
}

// ---------------------------------------------------------------------------
// 128x128x32 MFMA GEMM, B DIRECT-FROM-GLOBAL (fragment-prepacked, L1/L2-fed),
// A via LDS (gld_lds + swizzle). Register-double-buffered B (named brA/brB),
// unified counted vmcnt(6): per iter issue A-stage(tt+2) x2 then B(tt+2) x4.
// EPI 0: QKV split -> q, k, v^T (N=1536).  EPI 2: GELU -> bf16 (N=2048).
template <int EPI>
__global__ __launch_bounds__(256) void mfma_gemm(
    const u16* __restrict__ A, const u16* __restrict__ Bp,
    const float* __restrict__ bias,
    u16* __restrict__ Oq, u16* __restrict__ Ok, u16* __restrict__ Ovt,
    int M, int N, int K) {
  __shared__ u16 As[2][128 * 32];   // 16 KB total
  int t = threadIdx.x;
  int lane = t & 63, w = t >> 6;
  int wr = w >> 1, wc = w & 1;
  int l15 = lane & 15, l4 = lane >> 4;

  // XCD-chunked bijective remap, bm-fastest (co-resident blocks share bn
  // -> B fragments broadcast through L1).
  int gm = gridDim.y, gn = gridDim.x;
  int wgid = blockIdx.y * gn + blockIdx.x;
  int xcd = wgid & 7, c = wgid >> 3, rpx = gm >> 3;
  int bni = c / rpx;
  int bm = (xcd * rpx + (c - bni * rpx)) * 128;
  int bn = bni * 128;

  int gswu = ((t & 3) ^ ((t >> 3) & 3)) * 8;   // swizzled A source granule
  const u16* a0 = A + (size_t)(bm + (t >> 2)) * K + gswu;
  const u16* a1 = A + (size_t)(bm + 64 + (t >> 2)) * K + gswu;
  unsigned off0 = (unsigned)(t & 192) * 16u;
  unsigned off1 = off0 + 256u * 16u;
  int rxu = (l4 ^ ((l15 >> 1) & 3)) * 8;       // swizzled A read granule

  int nfr = K >> 5;                             // frags per 16-col strip
  const u16* bpw = Bp + ((size_t)((bn >> 4) + wc * 4) * nfr) * 512 + lane * 8;

  f32x4 acc[4][4];
  #pragma unroll
  for (int mi = 0; mi < 4; ++mi)
    #pragma unroll
    for (int nj = 0; nj < 4; ++nj)
      acc[mi][nj] = f32x4{0.f, 0.f, 0.f, 0.f};

  int nt = nfr;  // K/32 steps (16 for K=512) — always even

#define STAGE_A(ti, bi) do { int k0s = (ti) * 32;            \
    gld16(a0 + k0s, (char*)As[bi] + off0);                   \
    gld16(a1 + k0s, (char*)As[bi] + off1); } while (0)
#define LOADB(ti, breg) do {                                 \
    _Pragma("unroll") for (int nj = 0; nj < 4; ++nj)         \
      breg[nj] = *(const bf16x8*)(bpw + ((size_t)nj * nfr + (ti)) * 512); } while (0)

  bf16x8 brA[4], brB[4];
  STAGE_A(0, 0); LOADB(0, brA);
  STAGE_A(1, 1); LOADB(1, brB);

#define GSTEP(tt, breg) do {                                             \
    if ((tt) < nt - 1) asm volatile("s_waitcnt vmcnt(6)" ::: "memory");  \
    else               asm volatile("s_waitcnt vmcnt(0)" ::: "memory");  \
    __builtin_amdgcn_s_barrier();                                        \
    __builtin_amdgcn_sched_barrier(0);                                   \
    const u16* Asb = As[(tt) & 1];                                       \
    bf16x8 af[4];                                                        \
    _Pragma("unroll") for (int mi = 0; mi < 4; ++mi)                     \
      af[mi] = *(const bf16x8*)(Asb + (wr * 64 + mi * 16 + l15) * 32 + rxu); \
    _Pragma("unroll") for (int mi = 0; mi < 4; ++mi)                     \
      _Pragma("unroll") for (int nj = 0; nj < 4; ++nj)                   \
        acc[mi][nj] = __builtin_amdgcn_mfma_f32_16x16x32_bf16(af[mi], breg[nj], acc[mi][nj], 0, 0, 0); \
    __builtin_amdgcn_sched_barrier(0);                                   \
    __builtin_amdgcn_s_barrier();                                        \
    if ((tt) + 2 < nt) { STAGE_A((tt) + 2, (tt) & 1); LOADB((tt) + 2, breg); } \
  } while (0)

  for (int tt = 0; tt < nt; tt += 2) {
    GSTEP(tt, brA);
    GSTEP(tt + 1, brB);
  }
#undef GSTEP
#undef LOADB
#undef STAGE_A

  int row00 = bm + wr * 64, col0 = bn + wc * 64;
  #pragma unroll
  for (int mi = 0; mi < 4; ++mi) {
    int rowb = row00 + mi * 16 + l4 * 4;
    #pragma unroll
    for (int nj = 0; nj < 4; ++nj) {
      int col = col0 + nj * 16 + l15;
      float bcol = bias[col];
      if (EPI == 0) {
        if (col < 512) {
          #pragma unroll
          for (int r = 0; r < 4; ++r)
            Oq[(size_t)(rowb + r) * D + col] = f2bf(acc[mi][nj][r] + bcol);
        } else if (col < 1024) {
          #pragma unroll
          for (int r = 0; r < 4; ++r)
            Ok[(size_t)(rowb + r) * D + (col - 512)] = f2bf(acc[mi][nj][r] + bcol);
        } else {
          int cv = col - 1024;
          int hh = cv >> 6, dk = cv & 63;
          int bb = rowb / S, ss = rowb - bb * S;
          u16x4 pk;
          #pragma unroll
          for (int r = 0; r < 4; ++r) pk[r] = f2bf(acc[mi][nj][r] + bcol);
          *(u16x4*)(Ovt + ((size_t)(bb * H + hh) * DK + dk) * S + ss) = pk;
        }
      } else {  // GELU -> bf16
        #pragma unroll
        for (int r = 0; r < 4; ++r) {
          float v = acc[mi][nj][r] + bcol;
          v = 0.5f * v * (1.0f + erff(v * 0.70710678118654752f));
          Oq[(size_t)(rowb + r) * N + col] = f2bf(v);
        }
      }
    }
  }
}

// ---------------------------------------------------------------------------
// 64x128x32 GEMM for N=512 residual GEMMs (Wo, FFN2), B direct-from-global.
// LDS = A only (8 KB). vmcnt(5) steady (1 A-stage + 4 B-loads per iter).
__global__ __launch_bounds__(256) void gemm64(
    const u16* __restrict__ A, const u16* __restrict__ Bp,
    const float* __restrict__ bias, u16* __restrict__ Cres,
    int M, int N, int K) {
  __shared__ u16 As[2][64 * 32];    // 4 KB each
  int t = threadIdx.x;
  int lane = t & 63, w = t >> 6;
  int wr = w >> 1, wc = w & 1;      // wave: 32 rows x 64 cols

  int gm = gridDim.y, gn = gridDim.x;
  int wgid = blockIdx.y * gn + blockIdx.x;
  int xcd = wgid & 7, c = wgid >> 3, rpx = gm >> 3;
  int bni = c / rpx;
  int bm = (xcd * rpx + (c - bni * rpx)) * 64;
  int bn = bni * 128;

  int l15 = lane & 15, l4 = lane >> 4;

  int arow = t >> 2, ag = t & 3;
  int aswu = (ag ^ ((arow >> 1) & 3)) * 8;
  const u16* a0 = A + (size_t)(bm + arow) * K + aswu;
  unsigned offA = (unsigned)(w * 1024);
  int rxu = (l4 ^ ((l15 >> 1) & 3)) * 8;

  int nfr = K >> 5;
  const u16* bpw = Bp + ((size_t)((bn >> 4) + wc * 4) * nfr) * 512 + lane * 8;

  f32x4 acc[2][4];
  #pragma unroll
  for (int mi = 0; mi < 2; ++mi)
    #pragma unroll
    for (int nj = 0; nj < 4; ++nj)
      acc[mi][nj] = f32x4{0.f, 0.f, 0.f, 0.f};

  int nt = nfr;  // even (16 or 64)

#define STAGE_A(ti, bi) \
    gld16(a0 + (ti) * 32, (char*)As[bi] + offA)
#define LOADB(ti, breg) do {                                 \
    _Pragma("unroll") for (int nj = 0; nj < 4; ++nj)         \
      breg[nj] = *(const bf16x8*)(bpw + ((size_t)nj * nfr + (ti)) * 512); } while (0)

  bf16x8 brA[4], brB[4];
  STAGE_A(0, 0); LOADB(0, brA);
  STAGE_A(1, 1); LOADB(1, brB);

#define GSTEP(tt, breg) do {                                             \
    if ((tt) < nt - 1) asm volatile("s_waitcnt vmcnt(5)" ::: "memory");  \
    else               asm volatile("s_waitcnt vmcnt(0)" ::: "memory");  \
    __builtin_amdgcn_s_barrier();                                        \
    __builtin_amdgcn_sched_barrier(0);                                   \
    const u16* Asb = As[(tt) & 1];                                       \
    bf16x8 af[2];                                                        \
    _Pragma("unroll") for (int mi = 0; mi < 2; ++mi)                     \
      af[mi] = *(const bf16x8*)(Asb + (wr * 32 + mi * 16 + l15) * 32 + rxu); \
    _Pragma("unroll") for (int mi = 0; mi < 2; ++mi)                     \
      _Pragma("unroll") for (int nj = 0; nj < 4; ++nj)                   \
        acc[mi][nj] = __builtin_amdgcn_mfma_f32_16x16x32_bf16(af[mi], breg[nj], acc[mi][nj], 0, 0, 0); \
    __builtin_amdgcn_sched_barrier(0);                                   \
    __builtin_amdgcn_s_barrier();                                        \
    if ((tt) + 2 < nt) { STAGE_A((tt) + 2, (tt) & 1); LOADB((tt) + 2, breg); } \
  } while (0)

  for (int tt = 0; tt < nt; tt += 2) {
    GSTEP(tt, brA);
    GSTEP(tt + 1, brB);
  }
#undef GSTEP
#undef LOADB
#undef STAGE_A

  int row00 = bm + wr * 32, col0 = bn + wc * 64;
  #pragma unroll
  for (int mi = 0; mi < 2; ++mi) {
    int rowb = row00 + mi * 16 + l4 * 4;
    #pragma unroll
    for (int nj = 0; nj < 4; ++nj) {
      int col = col0 + nj * 16 + l15;
      float bcol = bias[col];
      #pragma unroll
      for (int r = 0; r < 4; ++r) {
        size_t ci = (size_t)(rowb + r) * N + col;
        Cres[ci] = f2bf(bf2f(Cres[ci]) + acc[mi][nj][r] + bcol);
      }
    }
  }
}

// ---------------------------------------------------------------------------
// MFMA flash attention (T14 async-STAGE + T5). Grid: (B*H, S/128).
__global__ __launch_bounds__(256) void attn_mfma(
    const u16* __restrict__ q, const u16* __restrict__ k,
    const u16* __restrict__ vt, const int* __restrict__ ids,
    u16* __restrict__ out) {
  __shared__ u16 Ks[64][72];
  __shared__ u16 Vs[64][72];
  __shared__ u16 Ps[4][32][72];
  __shared__ float Msall[S];
  int t = threadIdx.x, lane = t & 63, w = t >> 6;
  int l15 = lane & 15, l4 = lane >> 4;
  int bh = blockIdx.x;
  int b = bh >> 3, hh = bh & 7;
  int q0 = blockIdx.y * 128 + w * 32;

  for (int i = t; i < S; i += 256)
    Msall[i] = (ids[b * S + i] == 0) ? -1e9f : 0.0f;

  bf16x8 qf[2][2];
  const u16* qbase = q + (size_t)(b * S + q0) * D + hh * DK;
  #pragma unroll
  for (int mi = 0; mi < 2; ++mi)
    #pragma unroll
    for (int ks = 0; ks < 2; ++ks)
      qf[mi][ks] = *(const bf16x8*)(qbase + (size_t)(mi * 16 + l15) * D + ks * 32 + l4 * 8);

  int rr0 = t >> 3, ch0 = t & 7;
  int rr1 = (256 + t) >> 3, ch1 = t & 7;
  const size_t kbase = (size_t)(b * S) * D + hh * DK;
  const size_t vbase = (size_t)(b * H + hh) * DK * S;

  bf16x8 kr0, kr1, vr0, vr1;
  kr0 = *(const bf16x8*)(k + kbase + (size_t)rr0 * D + ch0 * 8);
  kr1 = *(const bf16x8*)(k + kbase + (size_t)rr1 * D + ch1 * 8);
  vr0 = *(const bf16x8*)(vt + vbase + (size_t)rr0 * S + 0 + ch0 * 8);
  vr1 = *(const bf16x8*)(vt + vbase + (size_t)rr1 * S + 0 + ch1 * 8);
  *(bf16x8*)(&Ks[rr0][ch0 * 8]) = kr0;
  *(bf16x8*)(&Ks[rr1][ch1 * 8]) = kr1;
  *(bf16x8*)(&Vs[rr0][ch0 * 8]) = vr0;
  *(bf16x8*)(&Vs[rr1][ch1 * 8]) = vr1;
  __syncthreads();

  float m[8], lsum[8];
  f32x4 accO[2][4];
  #pragma unroll
  for (int i = 0; i < 8; ++i) { m[i] = -3e38f; lsum[i] = 0.f; }
  #pragma unroll
  for (int mi = 0; mi < 2; ++mi)
    #pragma unroll
    for (int nj = 0; nj < 4; ++nj)
      accO[mi][nj] = f32x4{0.f, 0.f, 0.f, 0.f};

  for (int kb = 0; kb < S; kb += 64) {
    bool more = (kb + 64) < S;
    if (more) {
      kr0 = *(const bf16x8*)(k + kbase + (size_t)(kb + 64 + rr0) * D + ch0 * 8);
      kr1 = *(const bf16x8*)(k + kbase + (size_t)(kb + 64 + rr1) * D + ch1 * 8);
      vr0 = *(const bf16x8*)(vt + vbase + (size_t)rr0 * S + kb + 64 + ch0 * 8);
      vr1 = *(const bf16x8*)(vt + vbase + (size_t)rr1 * S + kb + 64 + ch1 * 8);
    }

    f32x4 sc[2][4];
    #pragma unroll
    for (int mi = 0; mi < 2; ++mi)
      #pragma unroll
      for (int nj = 0; nj < 4; ++nj)
        sc[mi][nj] = f32x4{0.f, 0.f, 0.f, 0.f};
    __builtin_amdgcn_s_setprio(1);
    #pragma unroll
    for (int ks = 0; ks < 2; ++ks) {
      bf16x8 kf[4];
      #pragma unroll
      for (int nj = 0; nj < 4; ++nj)
        kf[nj] = *(const bf16x8*)(&Ks[nj * 16 + l15][ks * 32 + l4 * 8]);
      #pragma unroll
      for (int mi = 0; mi < 2; ++mi)
        #pragma unroll
        for (int nj = 0; nj < 4; ++nj)
          sc[mi][nj] = __builtin_amdgcn_mfma_f32_16x16x32_bf16(qf[mi][ks], kf[nj], sc[mi][nj], 0, 0, 0);
    }
    __builtin_amdgcn_s_setprio(0);
    #pragma unroll
    for (int mi = 0; mi < 2; ++mi)
      #pragma unroll
      for (int nj = 0; nj < 4; ++nj) {
        float mv = Msall[kb + nj * 16 + l15];
        #pragma unroll
        for (int r = 0; r < 4; ++r)
          sc[mi][nj][r] = sc[mi][nj][r] * 0.125f + mv;
      }
    #pragma unroll
    for (int mi = 0; mi < 2; ++mi)
      #pragma unroll
      for (int r = 0; r < 4; ++r) {
        int ridx = mi * 4 + r;
        float mx = sc[mi][0][r];
        #pragma unroll
        for (int nj = 1; nj < 4; ++nj) mx = fmaxf(mx, sc[mi][nj][r]);
        #pragma unroll
        for (int o = 1; o < 16; o <<= 1) mx = fmaxf(mx, __shfl_xor(mx, o));
        float mnew = fmaxf(m[ridx], mx);
        float scale = __expf(m[ridx] - mnew);
        float rs = 0.f;
        #pragma unroll
        for (int nj = 0; nj < 4; ++nj) {
          float p = __expf(sc[mi][nj][r] - mnew);
          sc[mi][nj][r] = p;
          rs += p;
        }
        #pragma unroll
        for (int o = 1; o < 16; o <<= 1) rs += __shfl_xor(rs, o);
        lsum[ridx] = lsum[ridx] * scale + rs;
        m[ridx] = mnew;
        #pragma unroll
        for (int nj = 0; nj < 4; ++nj) accO[mi][nj][r] *= scale;
      }
    #pragma unroll
    for (int mi = 0; mi < 2; ++mi)
      #pragma unroll
      for (int nj = 0; nj < 4; ++nj)
        #pragma unroll
        for (int r = 0; r < 4; ++r)
          Ps[w][mi * 16 + l4 * 4 + r][nj * 16 + l15] = f2bf(sc[mi][nj][r]);
    __builtin_amdgcn_s_setprio(1);
    #pragma unroll
    for (int ks2 = 0; ks2 < 2; ++ks2) {
      bf16x8 pf[2], vf[4];
      #pragma unroll
      for (int mi = 0; mi < 2; ++mi)
        pf[mi] = *(const bf16x8*)(&Ps[w][mi * 16 + l15][ks2 * 32 + l4 * 8]);
      #pragma unroll
      for (int nj = 0; nj < 4; ++nj)
        vf[nj] = *(const bf16x8*)(&Vs[nj * 16 + l15][ks2 * 32 + l4 * 8]);
      #pragma unroll
      for (int mi = 0; mi < 2; ++mi)
        #pragma unroll
        for (int nj = 0; nj < 4; ++nj)
          accO[mi][nj] = __builtin_amdgcn_mfma_f32_16x16x32_bf16(pf[mi], vf[nj], accO[mi][nj], 0, 0, 0);
    }
    __builtin_amdgcn_s_setprio(0);

    if (more) {
      __syncthreads();
      *(bf16x8*)(&Ks[rr0][ch0 * 8]) = kr0;
      *(bf16x8*)(&Ks[rr1][ch1 * 8]) = kr1;
      *(bf16x8*)(&Vs[rr0][ch0 * 8]) = vr0;
      *(bf16x8*)(&Vs[rr1][ch1 * 8]) = vr1;
      __syncthreads();
    }
  }

  #pragma unroll
  for (int mi = 0; mi < 2; ++mi)
    #pragma unroll
    for (int nj = 0; nj < 4; ++nj)
      #pragma unroll
      for (int r = 0; r < 4; ++r) {
        int row = b * S + q0 + mi * 16 + l4 * 4 + r;
        out[(size_t)row * D + hh * DK + nj * 16 + l15] =
            f2bf(accO[mi][nj][r] / lsum[mi * 4 + r]);
      }
}

// ---------------------------------------------------------------------------
__global__ __launch_bounds__(512) void pool_part(
    const u16* __restrict__ x, const float* __restrict__ inten,
    float* __restrict__ part) {
  int b = blockIdx.x, cchunk = blockIdx.y;
  int d = threadIdx.x;
  int s0 = cchunk * 64;
  float acc = 0.f;
  for (int s = s0; s < s0 + 64; ++s)
    acc += inten[b * S + s] * bf2f(x[((size_t)b * S + s) * D + d]);
  part[((size_t)b * 6 + cchunk) * D + d] = acc;
}
__global__ __launch_bounds__(512) void pool_reduce(
    const float* __restrict__ part, float* __restrict__ out) {
  int b = blockIdx.x, d = threadIdx.x;
  float acc = 0.f;
  #pragma unroll
  for (int c = 0; c < 6; ++c) acc += part[((size_t)b * 6 + c) * D + d];
  out[b * D + d] = acc;
}

// ---------------------------------------------------------------------------
extern "C" void kernel_launch(void* const* d_in, const int* in_sizes, int n_in,
                              void* d_out, int out_size, void* d_ws, size_t ws_size,
                              hipStream_t stream) {
  const int* input_id    = (const int*)d_in[0];
  const float* intensity = (const float*)d_in[1];
  const float* emb = (const float*)d_in[2];
  const float* iw  = (const float*)d_in[3];
  const float* ib  = (const float*)d_in[4];
  const float* Wq  = (const float*)d_in[5];
  const float* bq  = (const float*)d_in[6];
  const float* Wk  = (const float*)d_in[7];
  const float* bk  = (const float*)d_in[8];
  const float* Wv  = (const float*)d_in[9];
  const float* bv  = (const float*)d_in[10];
  const float* Wo  = (const float*)d_in[11];
  const float* bo  = (const float*)d_in[12];
  const float* ln1w = (const float*)d_in[13];
  const float* ln1b = (const float*)d_in[14];
  const float* ln2w = (const float*)d_in[15];
  const float* ln2b = (const float*)d_in[16];
  const float* W1  = (const float*)d_in[17];
  const float* b1  = (const float*)d_in[18];
  const float* W2  = (const float*)d_in[19];
  const float* b2  = (const float*)d_in[20];
  float* outp = (float*)d_out;

  float *bqkv, *poolp;
  u16 *x, *h, *q, *k, *vt, *ffn, *qkvB, *woB, *w1B, *w2B;
  { void* p; hipGetSymbolAddress(&p, HIP_SYMBOL(g_x));    x    = (u16*)p; }
  { void* p; hipGetSymbolAddress(&p, HIP_SYMBOL(g_h));    h    = (u16*)p; }
  { void* p; hipGetSymbolAddress(&p, HIP_SYMBOL(g_q));    q    = (u16*)p; }
  { void* p; hipGetSymbolAddress(&p, HIP_SYMBOL(g_k));    k    = (u16*)p; }
  { void* p; hipGetSymbolAddress(&p, HIP_SYMBOL(g_vt));   vt   = (u16*)p; }
  { void* p; hipGetSymbolAddress(&p, HIP_SYMBOL(g_ffn));  ffn  = (u16*)p; }
  { void* p; hipGetSymbolAddress(&p, HIP_SYMBOL(g_qkvB)); qkvB = (u16*)p; }
  { void* p; hipGetSymbolAddress(&p, HIP_SYMBOL(g_woB));  woB  = (u16*)p; }
  { void* p; hipGetSymbolAddress(&p, HIP_SYMBOL(g_w1B));  w1B  = (u16*)p; }
  { void* p; hipGetSymbolAddress(&p, HIP_SYMBOL(g_w2B));  w2B  = (u16*)p; }
  { void* p; hipGetSymbolAddress(&p, HIP_SYMBOL(g_bqkv)); bqkv = (float*)p; }
  { void* p; hipGetSymbolAddress(&p, HIP_SYMBOL(g_pool)); poolp = (float*)p; }

  // ---- weight prep: fragment prepack (per launch; deterministic) ----
  dim3 t256(256);
  prepack_b<<<dim3(128, L), t256, 0, stream>>>(Wq, qkvB + 0 * D * D, D, D, (size_t)D * D, (size_t)3 * D * D);
  prepack_b<<<dim3(128, L), t256, 0, stream>>>(Wk, qkvB + 1 * D * D, D, D, (size_t)D * D, (size_t)3 * D * D);
  prepack_b<<<dim3(128, L), t256, 0, stream>>>(Wv, qkvB + 2 * D * D, D, D, (size_t)D * D, (size_t)3 * D * D);
  prepack_b<<<dim3(128, L), t256, 0, stream>>>(Wo, woB, D, D, (size_t)D * D, (size_t)D * D);
  prepack_b<<<dim3(512, L), t256, 0, stream>>>(W1, w1B, DFF, D, (size_t)D * DFF, (size_t)DFF * D);
  prepack_b<<<dim3(512, L), t256, 0, stream>>>(W2, w2B, D, DFF, (size_t)DFF * D, (size_t)D * DFF);
  concat_bias<<<L * 3 * D / 256, t256, 0, stream>>>(bq, bk, bv, bqkv);

  embed_kernel<<<TOK, t256, 0, stream>>>(input_id, intensity, emb, iw, ib, x);

  for (int l = 0; l < L; ++l) {
    const u16* qkvB_l = qkvB + (size_t)l * 3 * D * D;
    const u16* woB_l  = woB + (size_t)l * D * D;
    const u16* w1B_l  = w1B + (size_t)l * DFF * D;
    const u16* w2B_l  = w2B + (size_t)l * D * DFF;

    ln_kernel<<<TOK / 4, t256, 0, stream>>>(x, ln1w + (size_t)l * D, ln1b + (size_t)l * D, h);
    mfma_gemm<0><<<dim3(12, 96), t256, 0, stream>>>(h, qkvB_l, bqkv + l * 3 * D,
                                                    q, k, vt, TOK, 3 * D, D);
    attn_mfma<<<dim3(B * H, S / 128), t256, 0, stream>>>(q, k, vt, input_id, h);
    gemm64<<<dim3(4, 192), t256, 0, stream>>>(h, woB_l, bo + (size_t)l * D,
                                              x, TOK, D, D);
    ln_kernel<<<TOK / 4, t256, 0, stream>>>(x, ln2w + (size_t)l * D, ln2b + (size_t)l * D, h);
    mfma_gemm<2><<<dim3(16, 96), t256, 0, stream>>>(h, w1B_l, b1 + (size_t)l * DFF,
                                                    ffn, nullptr, nullptr, TOK, DFF, D);
    gemm64<<<dim3(4, 192), t256, 0, stream>>>(ffn, w2B_l, b2 + (size_t)l * D,
                                              x, TOK, D, DFF);
  }

  pool_part<<<dim3(B, 6), dim3(512), 0, stream>>>(x, intensity, poolp);
  pool_reduce<<<B, dim3(512), 0, stream>>>(poolp, outp);
}